// Round 11
// baseline (418.973 us; speedup 1.0000x reference)
//
#include <hip/hip_runtime.h>
#include <math.h>

// Problem constants: B=2,S=2048 -> T=4096, H=768, E=8, F=3072, K=2, BLOCK=16
#define T_TOK 4096
#define H_DIM 768
#define E_NUM 8
#define F_DIM 3072
#define EF_DIM 24576
#define SEG_MAX 9216
#define MAX_TILES 72

// meta ints
#define OFF_CNT      0
#define OFF_LAST     8
#define OFF_NT      40
#define OFF_TOTAL   41
#define OFF_SCHED_E 48
#define OFF_SCHED_G 120

// ws byte offsets
#define WS_SEL   768
#define WS_TOK   33536
#define WS_COEF  70400
#define WS_XG    107264ull     // bf16 Xg-frag[576][12][1024] = 14.16 MB ; reused as out-tmp for gemm2
#define WS_HG    14263040ull   // bf16 Hg-frag[576][48][1024] = 56.62 MB
#define WS_WT    70886144ull   // bf16 Wf (W1f then W2f, fragment-major) = 37.75 MB

typedef __attribute__((ext_vector_type(8))) short short8;
typedef __attribute__((ext_vector_type(4))) float float4v;

__device__ __forceinline__ short f2b(float f) {
  union { float f; unsigned u; } v; v.f = f;
  unsigned r = v.u + 0x7FFFu + ((v.u >> 16) & 1u);  // RNE
  return (short)(r >> 16);
}
__device__ __forceinline__ float b2f(short s) {
  union { unsigned u; float f; } v; v.u = ((unsigned)(unsigned short)s) << 16;
  return v.f;
}
// tanh-form gelu: max |diff| vs exact erf-gelu ~3e-3, far under the 6.5e-2 budget.
__device__ __forceinline__ float gelu_fast(float v) {
  const float z = 1.5957691216f * fmaf(0.044715f * v * v, v, v);
  return v / (1.0f + __expf(-z));
}

// ---------------- Router: logits (fp64 accum) + top-2 only. NO global atomics. ----------------
__global__ __launch_bounds__(256) void router_k(const float* __restrict__ x,
                                                const float* __restrict__ rw,
                                                float* __restrict__ logits_out,
                                                int* __restrict__ sel) {
  __shared__ float rws[E_NUM * H_DIM];
  for (int i = threadIdx.x; i < E_NUM * H_DIM; i += 256) rws[i] = rw[i];
  __syncthreads();
  const int wid = threadIdx.x >> 6, lane = threadIdx.x & 63;
  const int t = blockIdx.x * 4 + wid;
  const float* xr = x + (size_t)t * H_DIM;
  double acc[E_NUM];
#pragma unroll
  for (int e = 0; e < E_NUM; ++e) acc[e] = 0.0;
  for (int i = 0; i < H_DIM / 64; ++i) {
    const int h = lane + 64 * i;
    const float xv = xr[h];
#pragma unroll
    for (int e = 0; e < E_NUM; ++e) acc[e] += (double)xv * (double)rws[e * H_DIM + h];
  }
#pragma unroll
  for (int e = 0; e < E_NUM; ++e)
    for (int off = 32; off; off >>= 1) acc[e] += __shfl_down(acc[e], off);
  if (lane == 0) {
    float lg[E_NUM];
#pragma unroll
    for (int e = 0; e < E_NUM; ++e) { lg[e] = (float)acc[e]; logits_out[t * E_NUM + e] = lg[e]; }
    int e0 = 0;
    for (int e = 1; e < E_NUM; ++e) if (lg[e] > lg[e0]) e0 = e;
    int e1 = -1;
    for (int e = 0; e < E_NUM; ++e) {
      if (e == e0) continue;
      if (e1 < 0 || lg[e] > lg[e1]) e1 = e;
    }
    sel[t * 2 + 0] = e0;
    sel[t * 2 + 1] = e1;
  }
}

// ---------------- Histogram: one block per expert, ballot-reduce, no atomics ----------------
__global__ __launch_bounds__(1024) void hist_k(const int* __restrict__ sel,
                                               int* __restrict__ meta) {
  const int e = blockIdx.x;
  const int tid = threadIdx.x, lane = tid & 63, wid = tid >> 6;
  __shared__ int wcnt[16], wlast[16];
  int c = 0, lmax = 0;
#pragma unroll
  for (int it = 0; it < 8; ++it) {
    const int a = it * 1024 + tid;
    const unsigned long long mask = __ballot(sel[a] == e);
    if (lane == 0 && mask) {
      c += (int)__popcll(mask);
      const int hi = 63 - (int)__clzll((long long)mask);
      const int cand = a + hi + 1;  // a == wave base address since lane==0; store a_max+1
      lmax = lmax > cand ? lmax : cand;
    }
  }
  if (lane == 0) { wcnt[wid] = c; wlast[wid] = lmax; }
  __syncthreads();
  if (tid == 0) {
    int C = 0, L = 0;
    for (int w = 0; w < 16; ++w) { C += wcnt[w]; L = L > wlast[w] ? L : wlast[w]; }
    meta[OFF_CNT + e] = C;
    meta[OFF_LAST + e] = L;
  }
}

// ---------------- Scatter: one block per expert; stable ballot-rank, no atomics ----------------
// tok[g] stores the ASSIGNMENT id a (= 2*t + k), so pos_k can invert it.
__global__ __launch_bounds__(1024) void scatter_k(const int* __restrict__ sel,
                                                  int* __restrict__ meta,
                                                  int* __restrict__ tok,
                                                  float* __restrict__ coefv) {
  const int e = blockIdx.x;
  const int tid = threadIdx.x, lane = tid & 63, wid = tid >> 6;
  __shared__ int wv[16];

  int cnt[E_NUM];
#pragma unroll
  for (int i = 0; i < E_NUM; ++i) cnt[i] = meta[OFF_CNT + i];
  int seg = 0;
  for (int i = 0; i < e; ++i) seg += (cnt[i] + 127) & ~127;
  const int c = cnt[e];
  const int ru = (c + 127) & ~127;
  const int pad = (16 - (c & 15)) & 15;
  const int laste = meta[OFF_LAST + e];
  const float lastcoef = (float)(1 + pad);

  for (int p = c + tid; p < ru; p += 1024) { tok[seg + p] = -1; coefv[seg + p] = 0.0f; }
  if (e == E_NUM - 1) {
    const int total = seg + ru;
    for (int p = total + tid; p < SEG_MAX; p += 1024) { tok[p] = -1; coefv[p] = 0.0f; }
  }

  if (e == 0) {
    int nt = 0, s2 = 0;
    for (int i = 0; i < E_NUM; ++i) {
      const int rui = (cnt[i] + 127) & ~127;
      for (int m = 0; m < rui; m += 128) {
        if (nt == tid) { meta[OFF_SCHED_E + nt] = i; meta[OFF_SCHED_G + nt] = s2 + m; }
        ++nt;
      }
      s2 += rui;
    }
    if (tid >= nt && tid < MAX_TILES) { meta[OFF_SCHED_E + tid] = -1; meta[OFF_SCHED_G + tid] = 0; }
    if (tid == 0) { meta[OFF_NT] = nt; meta[OFF_TOTAL] = s2; }
  }

  int running = 0;
#pragma unroll
  for (int it = 0; it < 8; ++it) {
    const int a = it * 1024 + tid;
    const bool f = (sel[a] == e);
    const unsigned long long mask = __ballot(f);
    if (lane == 0) wv[wid] = (int)__popcll(mask);
    __syncthreads();
    int pre = 0, tot = 0;
#pragma unroll
    for (int w = 0; w < 16; ++w) { const int v = wv[w]; pre += (w < wid) ? v : 0; tot += v; }
    if (f) {
      const int rank = (int)__popcll(mask & ((1ull << lane) - 1ull));
      const int g = seg + running + pre + rank;
      tok[g] = a;  // assignment id, not token id
      coefv[g] = (laste == a + 1) ? lastcoef : 1.0f;
    }
    running += tot;
    __syncthreads();
  }
}

// ---------------- pos_k: invert tok -> pos[a] = g (written into dead sel region) ----------------
__global__ __launch_bounds__(256) void pos_k(const int* __restrict__ tok, int* __restrict__ pos) {
  const int g = blockIdx.x * 256 + threadIdx.x;
  const int a = tok[g];
  if (a >= 0) pos[a] = g;
}

// ---------------- Gather x rows -> bf16 Xg in FRAGMENT-MAJOR layout ----------------
// Xg-frag(g,k): blk = (g>>4)*12 + (k>>6); idx = blk*1024 + ((k>>3)&7)*128 + (g&15)*8 + (k&7)
__global__ __launch_bounds__(256) void gather_x_k(const float* __restrict__ x,
                                                  const int* __restrict__ tok,
                                                  short* __restrict__ xgf) {
  const int u = blockIdx.x * 256 + threadIdx.x;
  const int g = u / 96;
  const int c = (u - g * 96) * 8;
  const int a = tok[g];
  short8 v = {0, 0, 0, 0, 0, 0, 0, 0};
  if (a >= 0) {
    const float* src = x + (size_t)(a >> 1) * H_DIM + c;
    float4v f0 = *(const float4v*)src;
    float4v f1 = *(const float4v*)(src + 4);
    v[0] = f2b(f0[0]); v[1] = f2b(f0[1]); v[2] = f2b(f0[2]); v[3] = f2b(f0[3]);
    v[4] = f2b(f1[0]); v[5] = f2b(f1[1]); v[6] = f2b(f1[2]); v[7] = f2b(f1[3]);
  }
  const size_t dst = (size_t)((g >> 4) * 12 + (c >> 6)) * 1024 + ((c >> 3) & 7) * 128 + (g & 15) * 8;
  *(short8*)&xgf[dst] = v;
}

// ---------------- W1 [H][EF] f32 -> W1f fragment-major bf16 ----------------
__global__ __launch_bounds__(256) void conv_w1_k(const float* __restrict__ w1, short* __restrict__ w1f) {
  __shared__ float tile[64][65];
  const int n0 = blockIdx.x * 64;
  const int h0 = blockIdx.y * 64;
  const int tid = threadIdx.x;
  const int rr = tid >> 4;
  const int cc = (tid & 15) * 4;
#pragma unroll
  for (int p = 0; p < 4; ++p) {
    const int r = p * 16 + rr;
    float4v f = *(const float4v*)(w1 + (size_t)(h0 + r) * EF_DIM + n0 + cc);
    tile[r][cc] = f[0]; tile[r][cc + 1] = f[1]; tile[r][cc + 2] = f[2]; tile[r][cc + 3] = f[3];
  }
  __syncthreads();
#pragma unroll
  for (int p = 0; p < 2; ++p) {
    const int item = p * 256 + tid;
    const int nl = item >> 3;      // n local 0..63
    const int u8 = item & 7;       // k chunk 0..7 (8 shorts each)
    short8 v;
#pragma unroll
    for (int j = 0; j < 8; ++j) v[j] = f2b(tile[u8 * 8 + j][nl]);
    const size_t dst = (size_t)(((n0 + nl) >> 4) * (H_DIM / 64) + (h0 >> 6)) * 1024 +
                       u8 * 128 + (nl & 15) * 8;
    *(short8*)(w1f + dst) = v;
  }
}

// ---------------- W2 [EF][H] f32 -> W2f fragment-major bf16 ----------------
__global__ __launch_bounds__(256) void conv_w2_k(const float* __restrict__ w2, short* __restrict__ w2f) {
  __shared__ float tile[64][65];
  const int k0 = blockIdx.x * 64;   // over EF (f within expert)
  const int h0 = blockIdx.y * 64;
  const int e = k0 / F_DIM;
  const int f0 = k0 - e * F_DIM;
  const int tid = threadIdx.x;
  const int rr = tid >> 4;
  const int cc = (tid & 15) * 4;
#pragma unroll
  for (int p = 0; p < 4; ++p) {
    const int r = p * 16 + rr;
    float4v f = *(const float4v*)(w2 + (size_t)(k0 + r) * H_DIM + h0 + cc);
    tile[r][cc] = f[0]; tile[r][cc + 1] = f[1]; tile[r][cc + 2] = f[2]; tile[r][cc + 3] = f[3];
  }
  __syncthreads();
#pragma unroll
  for (int p = 0; p < 2; ++p) {
    const int item = p * 256 + tid;
    const int nl = item >> 3;      // h local 0..63
    const int u8 = item & 7;       // f chunk 0..7
    short8 v;
#pragma unroll
    for (int j = 0; j < 8; ++j) v[j] = f2b(tile[u8 * 8 + j][nl]);
    const size_t dst = (size_t)e * ((H_DIM / 16) * (F_DIM / 64) * 1024) +
                       (size_t)(((h0 + nl) >> 4) * (F_DIM / 64) + (f0 >> 6)) * 1024 +
                       u8 * 128 + (nl & 15) * 8;
    *(short8*)(w2f + dst) = v;
  }
}

// ==== GEMMs: ALL-REGISTER K-loop. A and B both fragment-major in global (1KB/wave
// coalesced loads), double-buffered in registers, consumed 1 iter after issue.
// ZERO LDS, ZERO barriers, ZERO inline-asm waits in the K-loop — each wave pipelines
// independently; compiler inserts counted waits. LDS used only for output transpose. ====

#define GG_ITER(T, ACUR, ANXT, BCUR, BNXT, NT, ASTR, BSTR, NJ)                         \
  {                                                                                    \
    const int tn_ = ((T) + 1 < (NT)) ? (T) + 1 : (T);                                  \
    _Pragma("unroll")                                                                  \
    for (int s = 0; s < 2; ++s)                                                        \
      _Pragma("unroll")                                                                \
      for (int i = 0; i < 4; ++i)                                                      \
        ANXT[s][i] = *(const short8*)(ab + (size_t)i * (ASTR) + tn_ * 1024 + s * 512); \
    _Pragma("unroll")                                                                  \
    for (int s = 0; s < 2; ++s)                                                        \
      _Pragma("unroll")                                                                \
      for (int j = 0; j < (NJ); ++j)                                                   \
        BNXT[s][j] = *(const short8*)(bb + (size_t)j * (BSTR) + tn_ * 1024 + s * 512); \
    _Pragma("unroll")                                                                  \
    for (int s = 0; s < 2; ++s)                                                        \
      _Pragma("unroll")                                                                \
      for (int i = 0; i < 4; ++i)                                                      \
        _Pragma("unroll")                                                              \
        for (int j = 0; j < (NJ); ++j)                                                 \
          acc[i][j] = __builtin_amdgcn_mfma_f32_16x16x32_bf16(ACUR[s][i], BCUR[s][j],  \
                                                              acc[i][j], 0, 0, 0);     \
  }

// ---------------- GEMM1: Hg = gelu(Xg @ W1f), fragment-major in and out ----------------
// grid: 1D, 24 * 72 = 1728 blocks. r7 slot-major chunked decode (proven fast).
__global__ __launch_bounds__(256, 2) void gemm1_k(const short* __restrict__ xgf,
                                                  const short* __restrict__ w1f,
                                                  const int* __restrict__ meta,
                                                  short* __restrict__ hgf) {
  const unsigned hwL = blockIdx.x;
  const unsigned logical = (hwL & 7u) * 216u + (hwL >> 3);
  const int slot = (int)(logical / 24u);
  const int n0 = (int)(logical % 24u) * 128;
  if (slot >= meta[OFF_NT]) return;
  const int e = meta[OFF_SCHED_E + slot];
  const int gbase = meta[OFF_SCHED_G + slot];

  __shared__ short Ep[128 * 128];  // 32 KB, epilogue transpose only

  const int tid = threadIdx.x;
  const int w = tid >> 6, l = tid & 63;
  const int mw = (w & 1) * 64, nw = (w >> 1) * 64;
  const int lrow = l & 15, q = l >> 4;

  const short* ab = xgf + (size_t)((gbase + mw) >> 4) * (12 * 1024) + l * 8;
  const short* bb = w1f + (size_t)((e * F_DIM + n0 + nw) >> 4) * (12 * 1024) + l * 8;

  float4v acc[4][4] = {};
  short8 aX[2][4], aY[2][4], bX[2][4], bY[2][4];

  // prologue: load tile 0 into X sets
#pragma unroll
  for (int s = 0; s < 2; ++s)
#pragma unroll
    for (int i = 0; i < 4; ++i)
      aX[s][i] = *(const short8*)(ab + (size_t)i * 12288 + s * 512);
#pragma unroll
  for (int s = 0; s < 2; ++s)
#pragma unroll
    for (int j = 0; j < 4; ++j)
      bX[s][j] = *(const short8*)(bb + (size_t)j * 12288 + s * 512);

  for (int t = 0; t < 12; t += 2) {
    GG_ITER(t, aX, aY, bX, bY, 12, 12288, 12288, 4)
    GG_ITER(t + 1, aY, aX, bY, bX, 12, 12288, 12288, 4)
  }

  // epilogue: gelu + bf16 via LDS transpose (XOR-swizzled), 16B fragment-major stores
#pragma unroll
  for (int i = 0; i < 4; ++i)
#pragma unroll
    for (int j = 0; j < 4; ++j)
#pragma unroll
      for (int r = 0; r < 4; ++r) {
        const int row = mw + 16 * i + q * 4 + r;
        const int col = nw + 16 * j + lrow;
        Ep[row * 128 + (col ^ ((row & 7) << 4))] = f2b(gelu_fast(acc[i][j][r]));
      }
  __syncthreads();
#pragma unroll
  for (int p = 0; p < 8; ++p) {
    const int item = p * 256 + tid;
    const int row = item >> 4;
    const int cc8 = (item & 15) * 8;
    const short8 v = *(const short8*)&Ep[row * 128 + (cc8 ^ ((row & 7) << 4))];
    const int f = n0 + cc8;
    const size_t dst = (size_t)((gbase + row) >> 4) * (48 * 1024) + (f >> 6) * 1024 +
                       ((f >> 3) & 7) * 128 + (row & 15) * 8;
    *(short8*)&hgf[dst] = v;
  }
}

// ---------------- GEMM2: tmp[g] = Hg @ W2f_e (bf16), 128x64 tiles, NO atomics ----------------
// grid: 1D, 12 * 72 = 864 blocks; r9 decode (A-panel shared within slot).
__global__ __launch_bounds__(256, 2) void gemm2_k(const short* __restrict__ hgf,
                                                  const short* __restrict__ w2f,
                                                  const int* __restrict__ meta,
                                                  short* __restrict__ tmp) {
  const unsigned hwL = blockIdx.x;
  const unsigned xcd = hwL & 7u;
  const unsigned l2 = hwL >> 3;              // 0..107
  const int slot = (int)(xcd * 9u + l2 / 12u);
  const int n0 = (int)(l2 % 12u) * 64;
  if (slot >= meta[OFF_NT]) return;
  const int e = meta[OFF_SCHED_E + slot];
  const int gbase = meta[OFF_SCHED_G + slot];

  __shared__ short Ep[128 * 128];  // 32 KB, epilogue only

  const int tid = threadIdx.x;
  const int w = tid >> 6, l = tid & 63;
  const int mw = (w & 1) * 64, nw = (w >> 1) * 32;   // 2M x 2N waves, 64x32 each
  const int lrow = l & 15, q = l >> 4;

  const short* ab = hgf + (size_t)((gbase + mw) >> 4) * (48 * 1024) + l * 8;
  const short* bb = w2f + (size_t)e * ((H_DIM / 16) * (F_DIM / 64) * 1024) +
                    (size_t)((n0 + nw) >> 4) * (48 * 1024) + l * 8;

  float4v acc[4][2] = {};
  short8 aX[2][4], aY[2][4], bX[2][2], bY[2][2];

  // prologue
#pragma unroll
  for (int s = 0; s < 2; ++s)
#pragma unroll
    for (int i = 0; i < 4; ++i)
      aX[s][i] = *(const short8*)(ab + (size_t)i * 49152 + s * 512);
#pragma unroll
  for (int s = 0; s < 2; ++s)
#pragma unroll
    for (int j = 0; j < 2; ++j)
      bX[s][j] = *(const short8*)(bb + (size_t)j * 49152 + s * 512);

  for (int t = 0; t < 48; t += 2) {
    GG_ITER(t, aX, aY, bX, bY, 48, 49152, 49152, 2)
    GG_ITER(t + 1, aY, aX, bY, bX, 48, 49152, 49152, 2)
  }

  // epilogue: bf16 tmp tile (128x64) via LDS transpose, 16B row-major stores (for combine)
#pragma unroll
  for (int i = 0; i < 4; ++i)
#pragma unroll
    for (int j = 0; j < 2; ++j)
#pragma unroll
      for (int r = 0; r < 4; ++r) {
        const int row = mw + 16 * i + q * 4 + r;
        const int col = nw + 16 * j + lrow;
        Ep[row * 128 + (col ^ ((row & 7) << 4))] = f2b(acc[i][j][r]);
      }
  __syncthreads();
#pragma unroll
  for (int p = 0; p < 4; ++p) {
    const int item = p * 256 + tid;
    const int row = item >> 3;
    const int cc8 = (item & 7) * 8;
    const short8 v = *(const short8*)&Ep[row * 128 + (cc8 ^ ((row & 7) << 4))];
    *(short8*)&tmp[(size_t)(gbase + row) * H_DIM + n0 + cc8] = v;
  }
}

// ---------------- Combine: out[t] = coef[g0]*tmp[g0] + coef[g1]*tmp[g1] ----------------
__global__ __launch_bounds__(256) void combine_k(const short* __restrict__ tmp,
                                                 const int* __restrict__ pos,
                                                 const float* __restrict__ coefv,
                                                 float* __restrict__ out) {
  const int u = blockIdx.x * 256 + threadIdx.x;
  const int t = u / 96;
  const int c = (u - t * 96) * 8;
  const int g0 = pos[t * 2 + 0];
  const int g1 = pos[t * 2 + 1];
  const float c0 = coefv[g0];
  const float c1 = coefv[g1];
  const short8 v0 = *(const short8*)&tmp[(size_t)g0 * H_DIM + c];
  const short8 v1 = *(const short8*)&tmp[(size_t)g1 * H_DIM + c];
  float r[8];
#pragma unroll
  for (int j = 0; j < 8; ++j) r[j] = c0 * b2f(v0[j]) + c1 * b2f(v1[j]);
  float4v* dst = (float4v*)&out[(size_t)t * H_DIM + c];
  dst[0] = (float4v){r[0], r[1], r[2], r[3]};
  dst[1] = (float4v){r[4], r[5], r[6], r[7]};
}

extern "C" void kernel_launch(void* const* d_in, const int* in_sizes, int n_in,
                              void* d_out, int out_size, void* d_ws, size_t ws_size,
                              hipStream_t stream) {
  const float* x  = (const float*)d_in[0];
  const float* rw = (const float*)d_in[1];
  const float* w1 = (const float*)d_in[2];
  const float* w2 = (const float*)d_in[3];
  float* out = (float*)d_out;
  float* logits = out + (size_t)T_TOK * H_DIM;

  char* ws = (char*)d_ws;
  int*   meta  = (int*)ws;
  int*   sel   = (int*)(ws + WS_SEL);   // after scatter_k this region becomes pos[8192]
  int*   tok   = (int*)(ws + WS_TOK);
  float* coefv = (float*)(ws + WS_COEF);
  short* xg    = (short*)(ws + WS_XG);  // Xg-frag for gemm1; reused as tmp for gemm2 output
  short* hg    = (short*)(ws + WS_HG);  // Hg-frag
  short* wt    = (short*)(ws + WS_WT);  // W1f then W2f (fragment-major)

  conv_w1_k<<<dim3(EF_DIM / 64, H_DIM / 64), 256, 0, stream>>>(w1, wt);
  router_k<<<T_TOK / 4, 256, 0, stream>>>(x, rw, logits, sel);
  hist_k<<<E_NUM, 1024, 0, stream>>>(sel, meta);
  scatter_k<<<E_NUM, 1024, 0, stream>>>(sel, meta, tok, coefv);
  pos_k<<<SEG_MAX / 256, 256, 0, stream>>>(tok, sel);  // sel region now = pos
  gather_x_k<<<(SEG_MAX * (H_DIM / 8)) / 256, 256, 0, stream>>>(x, tok, xg);
  gemm1_k<<<24 * MAX_TILES, 256, 0, stream>>>(xg, wt, meta, hg);
  conv_w2_k<<<dim3(EF_DIM / 64, H_DIM / 64), 256, 0, stream>>>(w2, wt);
  gemm2_k<<<12 * MAX_TILES, 256, 0, stream>>>(hg, wt, meta, xg);
  combine_k<<<(T_TOK * 96) / 256, 256, 0, stream>>>(xg, sel, coefv, out);
}

// Round 12
// 342.405 us; speedup vs baseline: 1.2236x; 1.2236x over previous
//
#include <hip/hip_runtime.h>
#include <math.h>

// Problem constants: B=2,S=2048 -> T=4096, H=768, E=8, F=3072, K=2, BLOCK=16
#define T_TOK 4096
#define H_DIM 768
#define E_NUM 8
#define F_DIM 3072
#define EF_DIM 24576
#define BK 64
#define SEG_MAX 9216
#define MAX_TILES 72
#define TILE_SH (128 * BK)   // shorts per LDS A-tile buffer

// meta ints
#define OFF_CNT      0
#define OFF_LAST     8
#define OFF_NT      40
#define OFF_TOTAL   41
#define OFF_SCHED_E 48
#define OFF_SCHED_G 120

// ws byte offsets
#define WS_SEL   768
#define WS_TOK   33536
#define WS_COEF  70400
#define WS_XG    107264ull     // bf16 Xg[9216][768] = 14.16 MB ; reused as out-tmp for gemm2
#define WS_HG    14263040ull   // bf16 Hg[9216][3072]  = 56.62 MB
#define WS_WT    70886144ull   // bf16 Wf (W1f then W2f, fragment-major, SHARED region) = 37.75 MB

typedef __attribute__((ext_vector_type(8))) short short8;
typedef __attribute__((ext_vector_type(4))) float float4v;

__device__ __forceinline__ short f2b(float f) {
  union { float f; unsigned u; } v; v.f = f;
  unsigned r = v.u + 0x7FFFu + ((v.u >> 16) & 1u);  // RNE
  return (short)(r >> 16);
}
__device__ __forceinline__ float b2f(short s) {
  union { unsigned u; float f; } v; v.u = ((unsigned)(unsigned short)s) << 16;
  return v.f;
}
// tanh-form gelu: max |diff| vs exact erf-gelu ~3e-3, far under the 6.5e-2 budget.
__device__ __forceinline__ float gelu_fast(float v) {
  const float z = 1.5957691216f * fmaf(0.044715f * v * v, v, v);
  return v / (1.0f + __expf(-z));
}
__device__ __forceinline__ void gl_lds16(const void* g, void* l) {
  __builtin_amdgcn_global_load_lds(
      (const __attribute__((address_space(1))) void*)g,
      (__attribute__((address_space(3))) void*)l, 16, 0, 0);
}

// ---------------- Router: logits (fp64 accum) + top-2 only. NO global atomics. ----------------
__global__ __launch_bounds__(256) void router_k(const float* __restrict__ x,
                                                const float* __restrict__ rw,
                                                float* __restrict__ logits_out,
                                                int* __restrict__ sel) {
  __shared__ float rws[E_NUM * H_DIM];
  for (int i = threadIdx.x; i < E_NUM * H_DIM; i += 256) rws[i] = rw[i];
  __syncthreads();
  const int wid = threadIdx.x >> 6, lane = threadIdx.x & 63;
  const int t = blockIdx.x * 4 + wid;
  const float* xr = x + (size_t)t * H_DIM;
  double acc[E_NUM];
#pragma unroll
  for (int e = 0; e < E_NUM; ++e) acc[e] = 0.0;
  for (int i = 0; i < H_DIM / 64; ++i) {
    const int h = lane + 64 * i;
    const float xv = xr[h];
#pragma unroll
    for (int e = 0; e < E_NUM; ++e) acc[e] += (double)xv * (double)rws[e * H_DIM + h];
  }
#pragma unroll
  for (int e = 0; e < E_NUM; ++e)
    for (int off = 32; off; off >>= 1) acc[e] += __shfl_down(acc[e], off);
  if (lane == 0) {
    float lg[E_NUM];
#pragma unroll
    for (int e = 0; e < E_NUM; ++e) { lg[e] = (float)acc[e]; logits_out[t * E_NUM + e] = lg[e]; }
    int e0 = 0;
    for (int e = 1; e < E_NUM; ++e) if (lg[e] > lg[e0]) e0 = e;
    int e1 = -1;
    for (int e = 0; e < E_NUM; ++e) {
      if (e == e0) continue;
      if (e1 < 0 || lg[e] > lg[e1]) e1 = e;
    }
    sel[t * 2 + 0] = e0;
    sel[t * 2 + 1] = e1;
  }
}

// ---------------- Histogram: one block per expert, ballot-reduce, no atomics ----------------
__global__ __launch_bounds__(1024) void hist_k(const int* __restrict__ sel,
                                               int* __restrict__ meta) {
  const int e = blockIdx.x;
  const int tid = threadIdx.x, lane = tid & 63, wid = tid >> 6;
  __shared__ int wcnt[16], wlast[16];
  int c = 0, lmax = 0;
#pragma unroll
  for (int it = 0; it < 8; ++it) {
    const int a = it * 1024 + tid;
    const unsigned long long mask = __ballot(sel[a] == e);
    if (lane == 0 && mask) {
      c += (int)__popcll(mask);
      const int hi = 63 - (int)__clzll((long long)mask);
      const int cand = a + hi + 1;  // a == wave base address since lane==0; store a_max+1
      lmax = lmax > cand ? lmax : cand;
    }
  }
  if (lane == 0) { wcnt[wid] = c; wlast[wid] = lmax; }
  __syncthreads();
  if (tid == 0) {
    int C = 0, L = 0;
    for (int w = 0; w < 16; ++w) { C += wcnt[w]; L = L > wlast[w] ? L : wlast[w]; }
    meta[OFF_CNT + e] = C;
    meta[OFF_LAST + e] = L;
  }
}

// ---------------- Scatter: one block per expert; stable ballot-rank, no atomics ----------------
// tok[g] stores the ASSIGNMENT id a (= 2*t + k), so pos_k can invert it.
__global__ __launch_bounds__(1024) void scatter_k(const int* __restrict__ sel,
                                                  int* __restrict__ meta,
                                                  int* __restrict__ tok,
                                                  float* __restrict__ coefv) {
  const int e = blockIdx.x;
  const int tid = threadIdx.x, lane = tid & 63, wid = tid >> 6;
  __shared__ int wv[16];

  int cnt[E_NUM];
#pragma unroll
  for (int i = 0; i < E_NUM; ++i) cnt[i] = meta[OFF_CNT + i];
  int seg = 0;
  for (int i = 0; i < e; ++i) seg += (cnt[i] + 127) & ~127;
  const int c = cnt[e];
  const int ru = (c + 127) & ~127;
  const int pad = (16 - (c & 15)) & 15;
  const int laste = meta[OFF_LAST + e];
  const float lastcoef = (float)(1 + pad);

  for (int p = c + tid; p < ru; p += 1024) { tok[seg + p] = -1; coefv[seg + p] = 0.0f; }
  if (e == E_NUM - 1) {
    const int total = seg + ru;
    for (int p = total + tid; p < SEG_MAX; p += 1024) { tok[p] = -1; coefv[p] = 0.0f; }
  }

  if (e == 0) {
    int nt = 0, s2 = 0;
    for (int i = 0; i < E_NUM; ++i) {
      const int rui = (cnt[i] + 127) & ~127;
      for (int m = 0; m < rui; m += 128) {
        if (nt == tid) { meta[OFF_SCHED_E + nt] = i; meta[OFF_SCHED_G + nt] = s2 + m; }
        ++nt;
      }
      s2 += rui;
    }
    if (tid >= nt && tid < MAX_TILES) { meta[OFF_SCHED_E + tid] = -1; meta[OFF_SCHED_G + tid] = 0; }
    if (tid == 0) { meta[OFF_NT] = nt; meta[OFF_TOTAL] = s2; }
  }

  int running = 0;
#pragma unroll
  for (int it = 0; it < 8; ++it) {
    const int a = it * 1024 + tid;
    const bool f = (sel[a] == e);
    const unsigned long long mask = __ballot(f);
    if (lane == 0) wv[wid] = (int)__popcll(mask);
    __syncthreads();
    int pre = 0, tot = 0;
#pragma unroll
    for (int w = 0; w < 16; ++w) { const int v = wv[w]; pre += (w < wid) ? v : 0; tot += v; }
    if (f) {
      const int rank = (int)__popcll(mask & ((1ull << lane) - 1ull));
      const int g = seg + running + pre + rank;
      tok[g] = a;  // assignment id, not token id
      coefv[g] = (laste == a + 1) ? lastcoef : 1.0f;
    }
    running += tot;
    __syncthreads();
  }
}

// ---------------- pos_k: invert tok -> pos[a] = g (written into dead sel region) ----------------
__global__ __launch_bounds__(256) void pos_k(const int* __restrict__ tok, int* __restrict__ pos) {
  const int g = blockIdx.x * 256 + threadIdx.x;
  const int a = tok[g];
  if (a >= 0) pos[a] = g;
}

// ---------------- Gather x rows -> bf16 Xg ----------------
__global__ __launch_bounds__(256) void gather_x_k(const float* __restrict__ x,
                                                  const int* __restrict__ tok,
                                                  short* __restrict__ xg) {
  const int u = blockIdx.x * 256 + threadIdx.x;
  const int g = u / 96;
  const int c = (u - g * 96) * 8;
  const int a = tok[g];
  short8 v = {0, 0, 0, 0, 0, 0, 0, 0};
  if (a >= 0) {
    const float* src = x + (size_t)(a >> 1) * H_DIM + c;
    float4v f0 = *(const float4v*)src;
    float4v f1 = *(const float4v*)(src + 4);
    v[0] = f2b(f0[0]); v[1] = f2b(f0[1]); v[2] = f2b(f0[2]); v[3] = f2b(f0[3]);
    v[4] = f2b(f1[0]); v[5] = f2b(f1[1]); v[6] = f2b(f1[2]); v[7] = f2b(f1[3]);
  }
  *(short8*)&xg[(size_t)g * H_DIM + c] = v;
}

// ---------------- W1 [H][EF] f32 -> W1f fragment-major bf16 ----------------
// W1f(n,k): blk = (n>>4)*(H/64) + (k>>6); short idx = blk*1024 + ((k>>3)&7)*128 + (n&15)*8 + (k&7)
__global__ __launch_bounds__(256) void conv_w1_k(const float* __restrict__ w1, short* __restrict__ w1f) {
  __shared__ float tile[64][65];
  const int n0 = blockIdx.x * 64;
  const int h0 = blockIdx.y * 64;
  const int tid = threadIdx.x;
  const int rr = tid >> 4;
  const int cc = (tid & 15) * 4;
#pragma unroll
  for (int p = 0; p < 4; ++p) {
    const int r = p * 16 + rr;
    float4v f = *(const float4v*)(w1 + (size_t)(h0 + r) * EF_DIM + n0 + cc);
    tile[r][cc] = f[0]; tile[r][cc + 1] = f[1]; tile[r][cc + 2] = f[2]; tile[r][cc + 3] = f[3];
  }
  __syncthreads();
#pragma unroll
  for (int p = 0; p < 2; ++p) {
    const int item = p * 256 + tid;
    const int nl = item >> 3;      // n local 0..63
    const int u8 = item & 7;       // k chunk 0..7 (8 shorts each)
    short8 v;
#pragma unroll
    for (int j = 0; j < 8; ++j) v[j] = f2b(tile[u8 * 8 + j][nl]);
    const size_t dst = (size_t)(((n0 + nl) >> 4) * (H_DIM / 64) + (h0 >> 6)) * 1024 +
                       u8 * 128 + (nl & 15) * 8;
    *(short8*)(w1f + dst) = v;
  }
}

// ---------------- W2 [EF][H] f32 -> W2f fragment-major bf16 ----------------
// W2f(e,n=h,k=f): e*(H/16)*(F/64)*1024 + ((n>>4)*(F/64)+(k>>6))*1024 + ((k>>3)&7)*128 + (n&15)*8 + (k&7)
__global__ __launch_bounds__(256) void conv_w2_k(const float* __restrict__ w2, short* __restrict__ w2f) {
  __shared__ float tile[64][65];
  const int k0 = blockIdx.x * 64;   // over EF (f within expert)
  const int h0 = blockIdx.y * 64;
  const int e = k0 / F_DIM;
  const int f0 = k0 - e * F_DIM;
  const int tid = threadIdx.x;
  const int rr = tid >> 4;
  const int cc = (tid & 15) * 4;
#pragma unroll
  for (int p = 0; p < 4; ++p) {
    const int r = p * 16 + rr;
    float4v f = *(const float4v*)(w2 + (size_t)(k0 + r) * H_DIM + h0 + cc);
    tile[r][cc] = f[0]; tile[r][cc + 1] = f[1]; tile[r][cc + 2] = f[2]; tile[r][cc + 3] = f[3];
  }
  __syncthreads();
#pragma unroll
  for (int p = 0; p < 2; ++p) {
    const int item = p * 256 + tid;
    const int nl = item >> 3;      // h local 0..63
    const int u8 = item & 7;       // f chunk 0..7
    short8 v;
#pragma unroll
    for (int j = 0; j < 8; ++j) v[j] = f2b(tile[u8 * 8 + j][nl]);
    const size_t dst = (size_t)e * ((H_DIM / 16) * (F_DIM / 64) * 1024) +
                       (size_t)(((h0 + nl) >> 4) * (F_DIM / 64) + (f0 >> 6)) * 1024 +
                       u8 * 128 + (nl & 15) * 8;
    *(short8*)(w2f + dst) = v;
  }
}

// ==== GEMMs (r7-proven): 128-tile, BK=64. A double-buffered in 32KB LDS (gl_lds, swizzled).
// B fragment-major from global, double-buffered in REGISTERS (consumed 1 iter after issue;
// the LDS-barrier anchor keeps the compiler from sinking the loads — r11 lesson).
// vmcnt(0) loop body (T4/T5 null on this 2-phase structure, r8).
// NEW this round: gemm1 __launch_bounds__(256,3) — fit 3 blocks/CU in the unified RF. ====

#define G_ITER(T, CB, BCUR, BNXT, NT, BSTR)                                            \
  {                                                                                    \
    const int nb_ = TILE_SH - (CB);                                                    \
    if ((T) + 1 < (NT)) {                                                              \
      const int k0n_ = ((T) + 1) * BK;                                                 \
      _Pragma("unroll")                                                                \
      for (int i = 0; i < 4; ++i) gl_lds16(agp[i] + k0n_, &As[nb_ + loff[i]]);         \
    }                                                                                  \
    const int tn_ = ((T) + 1 < (NT)) ? (T) + 1 : (T);                                  \
    _Pragma("unroll")                                                                  \
    for (int s = 0; s < 2; ++s)                                                        \
      _Pragma("unroll")                                                                \
      for (int j = 0; j < 4; ++j)                                                      \
        BNXT[s][j] = *(const short8*)(bb + (size_t)j * (BSTR) + tn_ * 1024 + s * 512); \
    short8 a_frag[2][4];                                                               \
    _Pragma("unroll")                                                                  \
    for (int s = 0; s < 2; ++s) {                                                      \
      const int csw_ = ((s * 4 + q) ^ rsw) * 8;                                        \
      _Pragma("unroll")                                                                \
      for (int i = 0; i < 4; ++i)                                                      \
        a_frag[s][i] = *(const short8*)&As[(CB) + (mw + 16 * i + lrow) * BK + csw_];   \
    }                                                                                  \
    _Pragma("unroll")                                                                  \
    for (int s = 0; s < 2; ++s)                                                        \
      _Pragma("unroll")                                                                \
      for (int i = 0; i < 4; ++i)                                                      \
        _Pragma("unroll")                                                              \
        for (int j = 0; j < 4; ++j)                                                    \
          acc[i][j] = __builtin_amdgcn_mfma_f32_16x16x32_bf16(a_frag[s][i], BCUR[s][j],\
                                                              acc[i][j], 0, 0, 0);     \
    asm volatile("s_waitcnt vmcnt(0) lgkmcnt(0)" ::: "memory");                        \
    __builtin_amdgcn_s_barrier();                                                      \
  }

// ---------------- GEMM1: Hg = gelu(Xg @ W1f) ----------------
// grid: 1D, 24 * 72 = 1728 blocks. r7 decode: slot-major within XCD (A-panel shared).
__global__ __launch_bounds__(256, 3) void gemm1_k(const short* __restrict__ xg,
                                                  const short* __restrict__ w1f,
                                                  const int* __restrict__ meta,
                                                  short* __restrict__ hg) {
  const unsigned hwL = blockIdx.x;
  const unsigned logical = (hwL & 7u) * 216u + (hwL >> 3);
  const int slot = (int)(logical / 24u);
  const int n0 = (int)(logical % 24u) * 128;
  if (slot >= meta[OFF_NT]) return;
  const int e = meta[OFF_SCHED_E + slot];
  const int gbase = meta[OFF_SCHED_G + slot];

  __shared__ short As[2 * TILE_SH];  // 32 KB, A only

  const int tid = threadIdx.x;
  const int w = tid >> 6, l = tid & 63;
  const int mw = (w & 1) * 64, nw = (w >> 1) * 64;
  const int lrow = l & 15, q = l >> 4;
  const int srow = l >> 3;
  const int schunk = (l & 7) ^ srow;

  const short* agp[4];
  int loff[4];
#pragma unroll
  for (int i = 0; i < 4; ++i) {
    const int r = i * 32 + w * 8 + srow;
    agp[i] = xg + (size_t)(gbase + r) * H_DIM + schunk * 8;
    loff[i] = (i * 32 + w * 8) * BK + l * 8;
  }
  const int rsw = lrow & 7;
  const short* bb = w1f + (size_t)((e * F_DIM + n0 + nw) >> 4) * ((H_DIM / 64) * 1024) +
                    q * 128 + lrow * 8;

  float4v acc[4][4] = {};
  short8 bX[2][4], bY[2][4];

  // prologue: stage A(0); load B(0) into bX
#pragma unroll
  for (int i = 0; i < 4; ++i) gl_lds16(agp[i], &As[loff[i]]);
#pragma unroll
  for (int s = 0; s < 2; ++s)
#pragma unroll
    for (int j = 0; j < 4; ++j)
      bX[s][j] = *(const short8*)(bb + (size_t)j * ((H_DIM / 64) * 1024) + s * 512);
  asm volatile("s_waitcnt vmcnt(0)" ::: "memory");
  __builtin_amdgcn_s_barrier();

  const int NT = H_DIM / BK;  // 12 (even)
  for (int t = 0; t < NT; t += 2) {
    G_ITER(t, 0, bX, bY, NT, (H_DIM / 64) * 1024)
    G_ITER(t + 1, TILE_SH, bY, bX, NT, (H_DIM / 64) * 1024)
  }

  // epilogue: gelu + bf16 via LDS transpose (XOR-swizzled), 16B stores
  short* Ep = As;  // 32 KB = 128x128 bf16
#pragma unroll
  for (int i = 0; i < 4; ++i)
#pragma unroll
    for (int j = 0; j < 4; ++j)
#pragma unroll
      for (int r = 0; r < 4; ++r) {
        const int row = mw + 16 * i + q * 4 + r;
        const int col = nw + 16 * j + lrow;
        Ep[row * 128 + (col ^ ((row & 7) << 4))] = f2b(gelu_fast(acc[i][j][r]));
      }
  __syncthreads();
#pragma unroll
  for (int p = 0; p < 8; ++p) {
    const int item = p * 256 + tid;
    const int row = item >> 4;
    const int cc8 = (item & 15) * 8;
    const short8 v = *(const short8*)&Ep[row * 128 + (cc8 ^ ((row & 7) << 4))];
    *(short8*)&hg[(size_t)(gbase + row) * F_DIM + n0 + cc8] = v;
  }
}

// ---------------- GEMM2: tmp[g] = Hg[g] @ W2f_e (bf16), NO atomics, NO split-K ----------------
// grid: 1D, 6 * 72 = 432 blocks (div by 8); r7 chunked decode.
__global__ __launch_bounds__(256, 2) void gemm2_k(const short* __restrict__ hg,
                                                  const short* __restrict__ w2f,
                                                  const int* __restrict__ meta,
                                                  short* __restrict__ tmp) {
  const unsigned hwL = blockIdx.x;
  const unsigned logical = (hwL & 7u) * 54u + (hwL >> 3);
  const int slot = (int)(logical / 6u);
  const int n0 = (int)(logical % 6u) * 128;
  if (slot >= meta[OFF_NT]) return;
  const int e = meta[OFF_SCHED_E + slot];
  const int gbase = meta[OFF_SCHED_G + slot];

  __shared__ short As[2 * TILE_SH];  // 32 KB, A only

  const int tid = threadIdx.x;
  const int w = tid >> 6, l = tid & 63;
  const int mw = (w & 1) * 64, nw = (w >> 1) * 64;
  const int lrow = l & 15, q = l >> 4;
  const int srow = l >> 3;
  const int schunk = (l & 7) ^ srow;

  const short* agp[4];
  int loff[4];
#pragma unroll
  for (int i = 0; i < 4; ++i) {
    const int r = i * 32 + w * 8 + srow;
    agp[i] = hg + (size_t)(gbase + r) * F_DIM + schunk * 8;
    loff[i] = (i * 32 + w * 8) * BK + l * 8;
  }
  const int rsw = lrow & 7;
  const short* bb = w2f + (size_t)e * ((H_DIM / 16) * (F_DIM / 64) * 1024) +
                    (size_t)((n0 + nw) >> 4) * ((F_DIM / 64) * 1024) +
                    q * 128 + lrow * 8;

  float4v acc[4][4] = {};
  short8 bX[2][4], bY[2][4];

  // prologue
#pragma unroll
  for (int i = 0; i < 4; ++i) gl_lds16(agp[i], &As[loff[i]]);
#pragma unroll
  for (int s = 0; s < 2; ++s)
#pragma unroll
    for (int j = 0; j < 4; ++j)
      bX[s][j] = *(const short8*)(bb + (size_t)j * ((F_DIM / 64) * 1024) + s * 512);
  asm volatile("s_waitcnt vmcnt(0)" ::: "memory");
  __builtin_amdgcn_s_barrier();

  const int NT = F_DIM / BK;  // 48 (even)
  for (int t = 0; t < NT; t += 2) {
    G_ITER(t, 0, bX, bY, NT, (F_DIM / 64) * 1024)
    G_ITER(t + 1, TILE_SH, bY, bX, NT, (F_DIM / 64) * 1024)
  }

  // epilogue: bf16 tmp tile via LDS transpose, 16B stores (no atomics)
  short* Ep = As;
#pragma unroll
  for (int i = 0; i < 4; ++i)
#pragma unroll
    for (int j = 0; j < 4; ++j)
#pragma unroll
      for (int r = 0; r < 4; ++r) {
        const int row = mw + 16 * i + q * 4 + r;
        const int col = nw + 16 * j + lrow;
        Ep[row * 128 + (col ^ ((row & 7) << 4))] = f2b(acc[i][j][r]);
      }
  __syncthreads();
#pragma unroll
  for (int p = 0; p < 8; ++p) {
    const int item = p * 256 + tid;
    const int row = item >> 4;
    const int cc8 = (item & 15) * 8;
    const short8 v = *(const short8*)&Ep[row * 128 + (cc8 ^ ((row & 7) << 4))];
    *(short8*)&tmp[(size_t)(gbase + row) * H_DIM + n0 + cc8] = v;
  }
}

// ---------------- Combine: out[t] = coef[g0]*tmp[g0] + coef[g1]*tmp[g1] ----------------
__global__ __launch_bounds__(256) void combine_k(const short* __restrict__ tmp,
                                                 const int* __restrict__ pos,
                                                 const float* __restrict__ coefv,
                                                 float* __restrict__ out) {
  const int u = blockIdx.x * 256 + threadIdx.x;
  const int t = u / 96;
  const int c = (u - t * 96) * 8;
  const int g0 = pos[t * 2 + 0];
  const int g1 = pos[t * 2 + 1];
  const float c0 = coefv[g0];
  const float c1 = coefv[g1];
  const short8 v0 = *(const short8*)&tmp[(size_t)g0 * H_DIM + c];
  const short8 v1 = *(const short8*)&tmp[(size_t)g1 * H_DIM + c];
  float r[8];
#pragma unroll
  for (int j = 0; j < 8; ++j) r[j] = c0 * b2f(v0[j]) + c1 * b2f(v1[j]);
  float4v* dst = (float4v*)&out[(size_t)t * H_DIM + c];
  dst[0] = (float4v){r[0], r[1], r[2], r[3]};
  dst[1] = (float4v){r[4], r[5], r[6], r[7]};
}

extern "C" void kernel_launch(void* const* d_in, const int* in_sizes, int n_in,
                              void* d_out, int out_size, void* d_ws, size_t ws_size,
                              hipStream_t stream) {
  const float* x  = (const float*)d_in[0];
  const float* rw = (const float*)d_in[1];
  const float* w1 = (const float*)d_in[2];
  const float* w2 = (const float*)d_in[3];
  float* out = (float*)d_out;
  float* logits = out + (size_t)T_TOK * H_DIM;

  char* ws = (char*)d_ws;
  int*   meta  = (int*)ws;
  int*   sel   = (int*)(ws + WS_SEL);   // after scatter_k this region becomes pos[8192]
  int*   tok   = (int*)(ws + WS_TOK);
  float* coefv = (float*)(ws + WS_COEF);
  short* xg    = (short*)(ws + WS_XG);  // Xg for gemm1; reused as tmp for gemm2 output
  short* hg    = (short*)(ws + WS_HG);
  short* wt    = (short*)(ws + WS_WT);  // W1f then W2f (fragment-major, shared region)

  conv_w1_k<<<dim3(EF_DIM / 64, H_DIM / 64), 256, 0, stream>>>(w1, wt);
  router_k<<<T_TOK / 4, 256, 0, stream>>>(x, rw, logits, sel);
  hist_k<<<E_NUM, 1024, 0, stream>>>(sel, meta);
  scatter_k<<<E_NUM, 1024, 0, stream>>>(sel, meta, tok, coefv);
  pos_k<<<SEG_MAX / 256, 256, 0, stream>>>(tok, sel);  // sel region now = pos
  gather_x_k<<<(SEG_MAX * (H_DIM / 8)) / 256, 256, 0, stream>>>(x, tok, xg);
  gemm1_k<<<24 * MAX_TILES, 256, 0, stream>>>(xg, wt, meta, hg);
  conv_w2_k<<<dim3(EF_DIM / 64, H_DIM / 64), 256, 0, stream>>>(w2, wt);
  gemm2_k<<<6 * MAX_TILES, 256, 0, stream>>>(hg, wt, meta, xg);
  combine_k<<<(T_TOK * 96) / 256, 256, 0, stream>>>(xg, sel, coefv, out);
}